// Round 4
// baseline (342.615 us; speedup 1.0000x reference)
//
#include <hip/hip_runtime.h>

#define NN 96
#define N3 (96*96*96)
#define EPS 0.0025f
#define DT  0.1f

__device__ __forceinline__ int wm(int i){ return i==0    ? NN-1 : i-1; }
__device__ __forceinline__ int wp(int i){ return i==NN-1 ? 0    : i+1; }
__device__ __forceinline__ int CB(int x,int y){ return (x*NN+y)*NN; }

// column-segment loaders: aligned float4 body + wrapped scalar halos
__device__ __forceinline__ void load8(const float* __restrict__ s, int cb,
    int z0,int zm2,int zm1,int zp4,int zp5, float* a){
  a[0]=s[cb+zm2]; a[1]=s[cb+zm1];
  float4 b = *(const float4*)(s+cb+z0);
  a[2]=b.x; a[3]=b.y; a[4]=b.z; a[5]=b.w;
  a[6]=s[cb+zp4]; a[7]=s[cb+zp5];
}
__device__ __forceinline__ void load6(const float* __restrict__ s, int cb,
    int z0,int zm1,int zp4, float* a){
  a[0]=s[cb+zm1];
  float4 b = *(const float4*)(s+cb+z0);
  a[1]=b.x; a[2]=b.y; a[3]=b.z; a[4]=b.w;
  a[5]=s[cb+zp4];
}
__device__ __forceinline__ void load4(const float* __restrict__ s, int cb, int z0, float* a){
  float4 b = *(const float4*)(s+cb+z0);
  a[0]=b.x; a[1]=b.y; a[2]=b.z; a[3]=b.w;
}

// AoS f32 [p][3] -> SoA f32 [c][p], 4 points per thread, all-vector
__global__ void k_convert(const float* __restrict__ in, float* __restrict__ v){
  int i = blockIdx.x*256 + threadIdx.x;           // segment of 4 points
  if (i >= N3/4) return;
  const float4* in4 = (const float4*)in;
  float4 a = in4[3*i], b = in4[3*i+1], c4 = in4[3*i+2];
  *(float4*)(v +          4*i) = make_float4(a.x, a.w, b.z, c4.y);
  *(float4*)(v + N3     + 4*i) = make_float4(a.y, b.x, b.w, c4.z);
  *(float4*)(v + 2*N3   + 4*i) = make_float4(a.z, b.y, c4.x, c4.w);
}

// Kernel A: dis_new = dis - dt*(grad(dis)·v + v), and t = t1+t2 (m = Lv on the fly).
template<int ZERO_DIS, int LAST>
__global__ __launch_bounds__(384) void k_A(const float* __restrict__ dis,
    const float* __restrict__ v, float* __restrict__ dout,
    float* __restrict__ t, float* __restrict__ out_ilv)
{
  int z0 = threadIdx.x*4;
  int y  = blockIdx.x*16 + threadIdx.y;
  int x  = blockIdx.y;
  int xm=wm(x), xp=wp(x), xm2=wm(xm), xp2=wp(xp);
  int ym=wm(y), yp=wp(y), ym2=wm(ym), yp2=wp(yp);
  int zm1 = (z0==0)?NN-1:z0-1, zm2 = (z0==0)?NN-2:z0-2;
  int zp4 = (z0==NN-4)?0:z0+4, zp5 = (z0==NN-4)?1:z0+5;

  int cbC=CB(x,y), cbXm=CB(xm,y), cbXp=CB(xp,y), cbYm=CB(x,ym), cbYp=CB(x,yp);
  int cbXm2=CB(xm2,y), cbXp2=CB(xp2,y), cbYm2=CB(x,ym2), cbYp2=CB(x,yp2);
  int cbMM=CB(xm,ym), cbMP=CB(xm,yp), cbPM=CB(xp,ym), cbPP=CB(xp,yp);
  int p0 = cbC + z0;

  float vv[3][4];
  #pragma unroll
  for (int c=0;c<3;c++) load4(v+c*N3, cbC, z0, vv[c]);

  // ---- dis update ----
  float r[3][4];
  #pragma unroll
  for (int c=0;c<3;c++){
    if (ZERO_DIS){
      #pragma unroll
      for (int k=0;k<4;k++) r[c][k] = -DT*vv[c][k];
    } else {
      const float* d = dis + c*N3;
      float dc[6], dxm[4], dxp[4], dym[4], dyp[4];
      load6(d, cbC, z0, zm1, zp4, dc);
      load4(d, cbXm, z0, dxm); load4(d, cbXp, z0, dxp);
      load4(d, cbYm, z0, dym); load4(d, cbYp, z0, dyp);
      #pragma unroll
      for (int k=0;k<4;k++){
        float w = 0.5f*( (dxp[k]-dxm[k])*vv[0][k]
                       + (dyp[k]-dym[k])*vv[1][k]
                       + (dc[k+2]-dc[k])*vv[2][k] );
        r[c][k] = dc[k+1] - DT*(w + vv[c][k]);
      }
    }
  }
  if (LAST){
    float4* ob = (float4*)(out_ilv + (size_t)p0*3);
    ob[0] = make_float4(r[0][0], r[1][0], r[2][0], r[0][1]);
    ob[1] = make_float4(r[1][1], r[2][1], r[0][2], r[1][2]);
    ob[2] = make_float4(r[2][2], r[0][3], r[1][3], r[2][3]);
    return;
  } else {
    #pragma unroll
    for (int c=0;c<3;c++)
      *(float4*)(dout + c*N3 + p0) = make_float4(r[c][0],r[c][1],r[c][2],r[c][3]);
  }

  // ---- t = t1 + t2, m recomputed on the fly ----
  float smc[3][6], sxm[3][4], sxp[3][4], sym[3][4], syp[3][4];
  float fvx_m[4], fvx_p[4], fvy_m[4], fvy_p[4], fvz_m[4], fvz_p[4];
  float t1a[3][4] = {{0,0,0,0},{0,0,0,0},{0,0,0,0}};

  #pragma unroll
  for (int c=0;c<3;c++){
    const float* s = v + c*N3;
    float vc[8], vxm_[6], vxp_[6], vym_[6], vyp_[6];
    float vxxm[4], vxxp[4], vyym[4], vyyp[4], vmm[4], vmp[4], vpm[4], vpp[4];
    load8(s, cbC, z0, zm2, zm1, zp4, zp5, vc);
    load6(s, cbXm, z0, zm1, zp4, vxm_); load6(s, cbXp, z0, zm1, zp4, vxp_);
    load6(s, cbYm, z0, zm1, zp4, vym_); load6(s, cbYp, z0, zm1, zp4, vyp_);
    load4(s, cbXm2, z0, vxxm); load4(s, cbXp2, z0, vxxp);
    load4(s, cbYm2, z0, vyym); load4(s, cbYp2, z0, vyyp);
    load4(s, cbMM, z0, vmm);   load4(s, cbMP, z0, vmp);
    load4(s, cbPM, z0, vpm);   load4(s, cbPP, z0, vpp);

    #pragma unroll
    for (int k=0;k<6;k++){
      float cen = vc[k+1];
      float nb  = vc[k]+vc[k+2]+vxm_[k]+vxp_[k]+vym_[k]+vyp_[k];
      smc[c][k] = fmaf(EPS, 6.f*cen - nb, cen);
    }
    #pragma unroll
    for (int k=0;k<4;k++){
      float cen, nb;
      cen = vxm_[k+1]; nb = vxm_[k]+vxm_[k+2]+vxxm[k]+vc[k+2]+vmm[k]+vmp[k];
      sxm[c][k] = fmaf(EPS, 6.f*cen - nb, cen);
      cen = vxp_[k+1]; nb = vxp_[k]+vxp_[k+2]+vc[k+2]+vxxp[k]+vpm[k]+vpp[k];
      sxp[c][k] = fmaf(EPS, 6.f*cen - nb, cen);
      cen = vym_[k+1]; nb = vym_[k]+vym_[k+2]+vmm[k]+vpm[k]+vyym[k]+vc[k+2];
      sym[c][k] = fmaf(EPS, 6.f*cen - nb, cen);
      cen = vyp_[k+1]; nb = vyp_[k]+vyp_[k+2]+vmp[k]+vpp[k]+vc[k+2]+vyyp[k];
      syp[c][k] = fmaf(EPS, 6.f*cen - nb, cen);
    }
    #pragma unroll
    for (int k=0;k<4;k++){
      float mcc = smc[c][k+1];
      t1a[0][k] = fmaf(vxp_[k+1]-vxm_[k+1], mcc, t1a[0][k]);
      t1a[1][k] = fmaf(vyp_[k+1]-vym_[k+1], mcc, t1a[1][k]);
      t1a[2][k] = fmaf(vc[k+3]-vc[k+1],     mcc, t1a[2][k]);
    }
    if (c==0){
      #pragma unroll
      for (int k=0;k<4;k++){ fvx_m[k]=vxm_[k+1]; fvx_p[k]=vxp_[k+1]; }
    } else if (c==1){
      #pragma unroll
      for (int k=0;k<4;k++){ fvy_m[k]=vym_[k+1]; fvy_p[k]=vyp_[k+1]; }
    } else {
      #pragma unroll
      for (int k=0;k<4;k++){ fvz_m[k]=vc[k+1]; fvz_p[k]=vc[k+3]; }
    }
  }

  #pragma unroll
  for (int i=0;i<3;i++){
    float ok[4];
    #pragma unroll
    for (int k=0;k<4;k++){
      float t2 = sxp[i][k]*fvx_p[k] - sxm[i][k]*fvx_m[k]
               + syp[i][k]*fvy_p[k] - sym[i][k]*fvy_m[k]
               + smc[i][k+2]*fvz_p[k] - smc[i][k]*fvz_m[k];
      ok[k] = 0.5f*(t1a[i][k] + t2);
    }
    *(float4*)(t + i*N3 + p0) = make_float4(ok[0],ok[1],ok[2],ok[3]);
  }
}

// Kernel C: v -= dt * (I - eps*A) t
__global__ __launch_bounds__(384) void k_C(const float* __restrict__ t, float* __restrict__ v)
{
  int z0 = threadIdx.x*4;
  int y  = blockIdx.x*16 + threadIdx.y;
  int x  = blockIdx.y;
  int xm=wm(x), xp=wp(x), ym=wm(y), yp=wp(y);
  int zm1 = (z0==0)?NN-1:z0-1, zp4 = (z0==NN-4)?0:z0+4;
  int cbC=CB(x,y), cbXm=CB(xm,y), cbXp=CB(xp,y), cbYm=CB(x,ym), cbYp=CB(x,yp);
  int p0 = cbC + z0;
  #pragma unroll
  for (int c=0;c<3;c++){
    const float* s = t + c*N3;
    float tc[6], txm[4], txp[4], tym[4], typ[4];
    load6(s, cbC, z0, zm1, zp4, tc);
    load4(s, cbXm, z0, txm); load4(s, cbXp, z0, txp);
    load4(s, cbYm, z0, tym); load4(s, cbYp, z0, typ);
    float4 vc = *(const float4*)(v + c*N3 + p0);
    float vn[4] = {vc.x, vc.y, vc.z, vc.w};
    #pragma unroll
    for (int k=0;k<4;k++){
      float cen = tc[k+1];
      float nb  = tc[k]+tc[k+2]+txm[k]+txp[k]+tym[k]+typ[k];
      float u = cen - EPS*(6.f*cen - nb);
      vn[k] -= DT*u;
    }
    *(float4*)(v + c*N3 + p0) = make_float4(vn[0],vn[1],vn[2],vn[3]);
  }
}

extern "C" void kernel_launch(void* const* d_in, const int* in_sizes, int n_in,
                              void* d_out, int out_size, void* d_ws, size_t ws_size,
                              hipStream_t stream)
{
  const float* v0 = (const float*)d_in[0];
  float* out = (float*)d_out;
  float* ws  = (float*)d_ws;

  float* v    = ws;            // 3*N3
  float* disA = v    + 3*N3;   // 3*N3
  float* disB = disA + 3*N3;   // 3*N3
  float* tbuf = disB + 3*N3;   // 3*N3

  dim3 blk(24,16,1), grd(6,96,1);

  k_convert<<<(N3/4+255)/256, 256, 0, stream>>>(v0, v);

  float* dcur  = disA;
  float* dfree = disB;

  for (int s=0; s<10; s++){
    if (s == 0){
      k_A<1,0><<<grd, blk, 0, stream>>>(nullptr, v, dcur, tbuf, nullptr);
    } else if (s == 9){
      k_A<0,1><<<grd, blk, 0, stream>>>(dcur, v, nullptr, nullptr, out);
      break;
    } else {
      k_A<0,0><<<grd, blk, 0, stream>>>(dcur, v, dfree, tbuf, nullptr);
      float* tmp = dcur; dcur = dfree; dfree = tmp;
    }
    k_C<<<grd, blk, 0, stream>>>(tbuf, v);
  }
}